// Round 13
// baseline (1801.195 us; speedup 1.0000x reference)
//
#include <hip/hip_runtime.h>
#include <hip/hip_bf16.h>

// Problem constants: B=256, T=512, D=64, H=256, C=10
#define Tt  512
#define Dd  64
#define CC  10

typedef short  short8 __attribute__((ext_vector_type(8)));
typedef __bf16 bf16x8 __attribute__((ext_vector_type(8)));
typedef float  f32x4  __attribute__((ext_vector_type(4)));

__device__ __forceinline__ unsigned short f2bf(float f) {
    unsigned u = __builtin_bit_cast(unsigned, f);
    u += 0x7fffu + ((u >> 16) & 1u);   // RNE
    return (unsigned short)(u >> 16);
}
__device__ __forceinline__ float bf2f(unsigned short s) {
    unsigned u = ((unsigned)s) << 16;
    return __builtin_bit_cast(float, u);
}
__device__ __forceinline__ float sigf(float x) {
    return __builtin_amdgcn_rcpf(1.0f + __expf(-x));
}
__device__ __forceinline__ float tanh_fast(float x) {
    return 1.0f - 2.0f * __builtin_amdgcn_rcpf(1.0f + __expf(2.0f * x));
}

// ---------------------------------------------------------------------------
// Pre-permute weights into per-lane MFMA A-fragment order (bf16).
// elem index = ((nf*10 + ks)*64 + lane)*8 + j
//   nf = h16*4 + gate;  k = ks*32 + (lane>>4)*8 + j  (k<256 -> W_hh else W_ih)
//   row = lane&15 -> n_orig = gate*256 + h16*16 + row
// ---------------------------------------------------------------------------
__global__ void prep_weights(const float* __restrict__ W_ih,
                             const float* __restrict__ W_hh,
                             unsigned short* __restrict__ Wc) {
    int id = blockIdx.x * blockDim.x + threadIdx.x;   // 0 .. 327679
    int j    = id & 7;
    int lane = (id >> 3) & 63;
    int rest = id >> 9;            // 0..639
    int ks   = rest % 10;
    int nf   = rest / 10;
    int k    = ks * 32 + ((lane >> 4) << 3) + j;
    int row  = lane & 15;
    int h16  = nf >> 2;
    int g    = nf & 3;
    int n_orig = g * 256 + h16 * 16 + row;
    float v = (k < 256) ? W_hh[n_orig * 256 + k]
                        : W_ih[n_orig * 64 + (k - 256)];
    Wc[id] = f2bf(v);
}

// biasp[h16*64 + g*16 + i] = b_ih[g*256+h16*16+i] + b_hh[...]  (i = hidx%16)
__global__ void prep_bias(const float* __restrict__ b_ih,
                          const float* __restrict__ b_hh,
                          float* __restrict__ biasp) {
    int tid = blockIdx.x * blockDim.x + threadIdx.x;  // 1024 threads
    if (tid < 1024) {
        int h16 = tid >> 6, g = (tid >> 4) & 3, i = tid & 15;
        int n_orig = g * 256 + h16 * 16 + i;
        biasp[tid] = b_ih[n_orig] + b_hh[n_orig];
    }
}

// ---------------------------------------------------------------------------
// Persistent LSTM, transposed GEMM (Z^T = W_cat @ [h;x]).
// Grid 64 WGs = 16 batch-groups (16 rows) x 4 hidx-parts (64 hidx).
// Wave w of WG(bg,p) owns h16 = p*4+w (16 hidx x 4 gates x 16 batches).
// h exchange: u64 agent-scope atomic exchange (producer) / atomic loads
// (consumer) at the MALL; publish = syncthreads + relaxed agent atomicAdd
// (R10/R11-proven, no fence in loop). R13 = R12 with the keep-alive pin in
// the SUPPORTED form (per-32-bit-scalar "+v"):
//  (1) weight/bias fragments pinned in VGPRs -> compiler cannot remat the
//      40 weight loads per step (was 160 KB/CU/step of L1/L2 reload).
//  (2) step order: poll -> issue h loads -> x-MFMA (overlaps h-load
//      flight) -> h-MFMA.
// ---------------------------------------------------------------------------
__global__ __launch_bounds__(256, 1) void lstm_persist(
    const float* __restrict__ x,
    const unsigned short* __restrict__ Wc,
    const float* __restrict__ biasp,
    unsigned short* __restrict__ h0buf,   // [256 batch][256 hidx] bf16
    unsigned short* __restrict__ h1buf,
    unsigned int* __restrict__ arrive,
    const float* __restrict__ W_out,
    const float* __restrict__ b_out,
    float* __restrict__ out)
{
    const int tid  = threadIdx.x;
    const int lane = tid & 63;
    const int w    = tid >> 6;
    const int bg   = blockIdx.x & 15;   // batch group 0..15
    const int p    = blockIdx.x >> 4;   // hidx part  0..3
    const int l15  = lane & 15;
    const int lhi  = lane >> 4;

    const int h16   = p * 4 + w;        // 0..15 (16-hidx chunk)
    const int batch = bg * 16 + l15;    // this lane's batch column

    unsigned int* cnt  = arrive + bg * 32;             // 128 B apart per group
    const float*  xrow = x + (size_t)batch * (Tt * Dd) + lhi * 8;

    // --- weights + bias into registers (pinned below) ----------------------
    uint4 wfraw[10][4];
    #pragma unroll
    for (int ks = 0; ks < 10; ++ks)
        #pragma unroll
        for (int g = 0; g < 4; ++g)
            wfraw[ks][g] = *reinterpret_cast<const uint4*>(
                Wc + (((h16 * 4 + g) * 10 + ks) * 64 + lane) * 8);
    uint4 bias_raw[4];
    #pragma unroll
    for (int g = 0; g < 4; ++g)
        bias_raw[g] = *reinterpret_cast<const uint4*>(
            biasp + h16 * 64 + g * 16 + lhi * 4);

    // x(t=0)
    float4 xq0 = *reinterpret_cast<const float4*>(xrow);
    float4 xq1 = *reinterpret_cast<const float4*>(xrow + 4);
    float4 xq2 = *reinterpret_cast<const float4*>(xrow + 32);
    float4 xq3 = *reinterpret_cast<const float4*>(xrow + 36);

    f32x4 creg = (f32x4){0.f, 0.f, 0.f, 0.f};

    for (int t = 0; t < Tt; ++t) {
        // 0) keep-alive pin (per-scalar "+v", the supported form): weights/
        //    bias become loop-carried opaque values -> no remat, stay in VGPR.
        #pragma unroll
        for (int ks = 0; ks < 10; ++ks)
            #pragma unroll
            for (int g = 0; g < 4; ++g)
                asm volatile("" : "+v"(wfraw[ks][g].x), "+v"(wfraw[ks][g].y),
                                  "+v"(wfraw[ks][g].z), "+v"(wfraw[ks][g].w));
        #pragma unroll
        for (int g = 0; g < 4; ++g)
            asm volatile("" : "+v"(bias_raw[g].x), "+v"(bias_raw[g].y),
                              "+v"(bias_raw[g].z), "+v"(bias_raw[g].w));

        // 1) wait for h_t, then ISSUE h loads (agent atomics, tracked)
        ulonglong2 hv[8];
        if (t > 0) {
            const unsigned target = 4u * (unsigned)t;
            if (lane == 0) {
                while (__hip_atomic_load(cnt, __ATOMIC_RELAXED,
                                         __HIP_MEMORY_SCOPE_AGENT) < target) {}
            }
            __builtin_amdgcn_sched_barrier(0);   // loads stay below the poll
            const unsigned short* hin = (t & 1) ? h1buf : h0buf;
            const unsigned long long* hin64 =
                reinterpret_cast<const unsigned long long*>(
                    hin + batch * 256 + lhi * 8);
            #pragma unroll
            for (int ks = 0; ks < 8; ++ks) {
                hv[ks].x = __hip_atomic_load(hin64 + ks * 8,
                                             __ATOMIC_RELAXED, __HIP_MEMORY_SCOPE_AGENT);
                hv[ks].y = __hip_atomic_load(hin64 + ks * 8 + 1,
                                             __ATOMIC_RELAXED, __HIP_MEMORY_SCOPE_AGENT);
            }
        }

        // 2) x contribution — independent of h loads; overlaps their flight
        f32x4 acc[4];
        #pragma unroll
        for (int g = 0; g < 4; ++g)
            acc[g] = __builtin_bit_cast(f32x4, bias_raw[g]);
        {
            short8 a8 = (short8){ (short)f2bf(xq0.x), (short)f2bf(xq0.y),
                                  (short)f2bf(xq0.z), (short)f2bf(xq0.w),
                                  (short)f2bf(xq1.x), (short)f2bf(xq1.y),
                                  (short)f2bf(xq1.z), (short)f2bf(xq1.w) };
            short8 a9 = (short8){ (short)f2bf(xq2.x), (short)f2bf(xq2.y),
                                  (short)f2bf(xq2.z), (short)f2bf(xq2.w),
                                  (short)f2bf(xq3.x), (short)f2bf(xq3.y),
                                  (short)f2bf(xq3.z), (short)f2bf(xq3.w) };
            bf16x8 bv8 = __builtin_bit_cast(bf16x8, a8);
            bf16x8 bv9 = __builtin_bit_cast(bf16x8, a9);
            #pragma unroll
            for (int g = 0; g < 4; ++g) {
                acc[g] = __builtin_amdgcn_mfma_f32_16x16x32_bf16(
                    __builtin_bit_cast(bf16x8, wfraw[8][g]), bv8, acc[g], 0, 0, 0);
                acc[g] = __builtin_amdgcn_mfma_f32_16x16x32_bf16(
                    __builtin_bit_cast(bf16x8, wfraw[9][g]), bv9, acc[g], 0, 0, 0);
            }
        }

        // 3) recurrent contribution (compiler waits on the h loads here)
        if (t > 0) {
            #pragma unroll
            for (int ks = 0; ks < 8; ++ks) {
                bf16x8 bv = __builtin_bit_cast(bf16x8, hv[ks]);
                #pragma unroll
                for (int g = 0; g < 4; ++g)
                    acc[g] = __builtin_amdgcn_mfma_f32_16x16x32_bf16(
                        __builtin_bit_cast(bf16x8, wfraw[ks][g]), bv, acc[g], 0, 0, 0);
            }
        }

        // 4) gates + c/h update; pack 4 consecutive-hidx h -> one u64 SWAP
        unsigned short* hout = ((t + 1) & 1) ? h1buf : h0buf;
        unsigned long long hpack = 0;
        #pragma unroll
        for (int r = 0; r < 4; ++r) {
            float cn = sigf(acc[1][r]) * creg[r] + sigf(acc[0][r]) * tanh_fast(acc[2][r]);
            float hn = sigf(acc[3][r]) * tanh_fast(cn);
            creg[r] = cn;
            hpack |= (unsigned long long)f2bf(hn) << (16 * r);
        }
        {
            unsigned long long* hp = reinterpret_cast<unsigned long long*>(
                hout + batch * 256 + h16 * 16 + lhi * 4);
            (void)__hip_atomic_exchange(hp, hpack, __ATOMIC_RELAXED,
                                        __HIP_MEMORY_SCOPE_AGENT);
        }

        // 5) prefetch x for t+1 (plain cached; drained by the barrier)
        if (t + 1 < Tt) {
            const float* xp = xrow + (size_t)(t + 1) * Dd;
            xq0 = *reinterpret_cast<const float4*>(xp);
            xq1 = *reinterpret_cast<const float4*>(xp + 4);
            xq2 = *reinterpret_cast<const float4*>(xp + 32);
            xq3 = *reinterpret_cast<const float4*>(xp + 36);
        }

        // 6) publish: barrier (drains swaps via vmcnt(0)) + relaxed atomicAdd
        __syncthreads();
        if (tid == 0) {
            __hip_atomic_fetch_add(cnt, 1u, __ATOMIC_RELAXED,
                                   __HIP_MEMORY_SCOPE_AGENT);
        }
    }

    // --- output head: p==0 WGs handle their 16 batches (one-time acquire) --
    if (p == 0) {
        if (lane == 0) {
            while (__hip_atomic_load(cnt, __ATOMIC_RELAXED,
                                     __HIP_MEMORY_SCOPE_AGENT) < 4u * Tt) {}
        }
        __builtin_amdgcn_fence(__ATOMIC_ACQUIRE, "agent");
        const unsigned short* hT = h0buf;   // Tt even -> final h in buf 0
        #pragma unroll 1
        for (int rr = 0; rr < 4; ++rr) {
            int row = bg * 16 + w * 4 + rr;
            ushort4 hu = *reinterpret_cast<const ushort4*>(hT + row * 256 + lane * 4);
            float f0 = bf2f(hu.x), f1 = bf2f(hu.y), f2 = bf2f(hu.z), f3 = bf2f(hu.w);
            #pragma unroll 1
            for (int cls = 0; cls < CC; ++cls) {
                float4 wv = *reinterpret_cast<const float4*>(W_out + cls * 256 + lane * 4);
                float pr = f0 * wv.x + f1 * wv.y + f2 * wv.z + f3 * wv.w;
                #pragma unroll
                for (int off = 32; off > 0; off >>= 1) pr += __shfl_down(pr, off);
                if (lane == 0) out[row * CC + cls] = sigf(pr + b_out[cls]);
            }
        }
    }
}

extern "C" void kernel_launch(void* const* d_in, const int* in_sizes, int n_in,
                              void* d_out, int out_size, void* d_ws, size_t ws_size,
                              hipStream_t stream) {
    const float* x     = (const float*)d_in[0];
    const float* W_ih  = (const float*)d_in[1];
    const float* W_hh  = (const float*)d_in[2];
    const float* b_ih  = (const float*)d_in[3];
    const float* b_hh  = (const float*)d_in[4];
    const float* W_out = (const float*)d_in[5];
    const float* b_out = (const float*)d_in[6];
    float* out = (float*)d_out;

    // workspace layout (~924 KB)
    char* ws = (char*)d_ws;
    unsigned short* Wc    = (unsigned short*)(ws);            // 655360 B
    float*          biasp = (float*)(ws + 655360);            //   4096 B
    unsigned short* h0    = (unsigned short*)(ws + 659456);   // 131072 B
    unsigned short* h1    = (unsigned short*)(ws + 790528);   // 131072 B
    unsigned int*   arr   = (unsigned int*)(ws + 921600);     //   2048 B

    hipLaunchKernelGGL(prep_weights, dim3(1280), dim3(256), 0, stream, W_ih, W_hh, Wc);
    hipLaunchKernelGGL(prep_bias,    dim3(4),    dim3(256), 0, stream, b_ih, b_hh, biasp);
    hipMemsetAsync(arr, 0, 2048, stream);

    hipLaunchKernelGGL(lstm_persist, dim3(64), dim3(256), 0, stream,
                       x, Wc, biasp, h0, h1, arr, W_out, b_out, out);
}

// Round 14
// 1196.290 us; speedup vs baseline: 1.5057x; 1.5057x over previous
//
#include <hip/hip_runtime.h>
#include <hip/hip_bf16.h>

// Problem constants: B=256, T=512, D=64, H=256, C=10
#define Tt  512
#define Dd  64
#define CC  10

typedef short  short8 __attribute__((ext_vector_type(8)));
typedef __bf16 bf16x8 __attribute__((ext_vector_type(8)));
typedef float  f32x4  __attribute__((ext_vector_type(4)));
typedef int    int4v  __attribute__((ext_vector_type(4)));

__device__ __forceinline__ unsigned short f2bf(float f) {
    unsigned u = __builtin_bit_cast(unsigned, f);
    u += 0x7fffu + ((u >> 16) & 1u);   // RNE
    return (unsigned short)(u >> 16);
}
__device__ __forceinline__ float bf2f(unsigned short s) {
    unsigned u = ((unsigned)s) << 16;
    return __builtin_bit_cast(float, u);
}
__device__ __forceinline__ float sigf(float x) {
    return __builtin_amdgcn_rcpf(1.0f + __expf(-x));
}
__device__ __forceinline__ float tanh_fast(float x) {
    return 1.0f - 2.0f * __builtin_amdgcn_rcpf(1.0f + __expf(2.0f * x));
}

// ---------------------------------------------------------------------------
// Pre-permute weights into per-lane MFMA A-fragment order (bf16).
// elem index = ((nf*10 + ks)*64 + lane)*8 + j
//   nf = h16*4 + gate;  k = ks*32 + (lane>>4)*8 + j  (k<256 -> W_hh else W_ih)
//   row = lane&15 -> n_orig = gate*256 + h16*16 + row
// ---------------------------------------------------------------------------
__global__ void prep_weights(const float* __restrict__ W_ih,
                             const float* __restrict__ W_hh,
                             unsigned short* __restrict__ Wc) {
    int id = blockIdx.x * blockDim.x + threadIdx.x;   // 0 .. 327679
    int j    = id & 7;
    int lane = (id >> 3) & 63;
    int rest = id >> 9;            // 0..639
    int ks   = rest % 10;
    int nf   = rest / 10;
    int k    = ks * 32 + ((lane >> 4) << 3) + j;
    int row  = lane & 15;
    int h16  = nf >> 2;
    int g    = nf & 3;
    int n_orig = g * 256 + h16 * 16 + row;
    float v = (k < 256) ? W_hh[n_orig * 256 + k]
                        : W_ih[n_orig * 64 + (k - 256)];
    Wc[id] = f2bf(v);
}

// biasp[h16*64 + g*16 + i] = b_ih[g*256+h16*16+i] + b_hh[...]  (i = hidx%16)
__global__ void prep_bias(const float* __restrict__ b_ih,
                          const float* __restrict__ b_hh,
                          float* __restrict__ biasp) {
    int tid = blockIdx.x * blockDim.x + threadIdx.x;  // 1024 threads
    if (tid < 1024) {
        int h16 = tid >> 6, g = (tid >> 4) & 3, i = tid & 15;
        int n_orig = g * 256 + h16 * 16 + i;
        biasp[tid] = b_ih[n_orig] + b_hh[n_orig];
    }
}

// ---------------------------------------------------------------------------
// Persistent LSTM, transposed GEMM (Z^T = W_cat @ [h;x]).
// Grid 64 WGs = 16 batch-groups (16 rows) x 4 hidx-parts (64 hidx).
// Wave w of WG(bg,p) owns h16 = p*4+w (16 hidx x 4 gates x 16 batches).
// h exchange: u64 agent-scope atomic exchange (producer, R10/R11-proven) /
// ONE fused asm block of 8 parallel sc0sc1 dwordx4 loads + single vmcnt(0)
// (consumer — replaces 16 SERIALIZED atomic loads = ~16 MALL RTTs with ~1).
// Publish: syncthreads + relaxed agent atomicAdd; no fence in the loop.
// ---------------------------------------------------------------------------
__global__ __launch_bounds__(256, 1) void lstm_persist(
    const float* __restrict__ x,
    const unsigned short* __restrict__ Wc,
    const float* __restrict__ biasp,
    unsigned short* __restrict__ h0buf,   // [256 batch][256 hidx] bf16
    unsigned short* __restrict__ h1buf,
    unsigned int* __restrict__ arrive,
    const float* __restrict__ W_out,
    const float* __restrict__ b_out,
    float* __restrict__ out)
{
    const int tid  = threadIdx.x;
    const int lane = tid & 63;
    const int w    = tid >> 6;
    const int bg   = blockIdx.x & 15;   // batch group 0..15
    const int p    = blockIdx.x >> 4;   // hidx part  0..3
    const int l15  = lane & 15;
    const int lhi  = lane >> 4;

    const int h16   = p * 4 + w;        // 0..15 (16-hidx chunk)
    const int batch = bg * 16 + l15;    // this lane's batch column

    unsigned int* cnt  = arrive + bg * 32;             // 128 B apart per group
    const float*  xrow = x + (size_t)batch * (Tt * Dd) + lhi * 8;

    // --- weights + bias (plain cached loads; L2 stays warm all loop) -------
    bf16x8 wfrag[10][4];
    #pragma unroll
    for (int ks = 0; ks < 10; ++ks)
        #pragma unroll
        for (int g = 0; g < 4; ++g)
            wfrag[ks][g] = __builtin_bit_cast(bf16x8,
                *reinterpret_cast<const short8*>(
                    Wc + (((h16 * 4 + g) * 10 + ks) * 64 + lane) * 8));
    f32x4 bias_r[4];
    #pragma unroll
    for (int g = 0; g < 4; ++g)
        bias_r[g] = __builtin_bit_cast(f32x4,
            *reinterpret_cast<const float4*>(biasp + h16 * 64 + g * 16 + lhi * 4));

    // x(t=0)
    float4 xq0 = *reinterpret_cast<const float4*>(xrow);
    float4 xq1 = *reinterpret_cast<const float4*>(xrow + 4);
    float4 xq2 = *reinterpret_cast<const float4*>(xrow + 32);
    float4 xq3 = *reinterpret_cast<const float4*>(xrow + 36);

    f32x4 creg = (f32x4){0.f, 0.f, 0.f, 0.f};

    for (int t = 0; t < Tt; ++t) {
        // 1) x contribution (B-fragment from x; A = weights)
        f32x4 acc[4];
        #pragma unroll
        for (int g = 0; g < 4; ++g) acc[g] = bias_r[g];
        {
            short8 a8 = (short8){ (short)f2bf(xq0.x), (short)f2bf(xq0.y),
                                  (short)f2bf(xq0.z), (short)f2bf(xq0.w),
                                  (short)f2bf(xq1.x), (short)f2bf(xq1.y),
                                  (short)f2bf(xq1.z), (short)f2bf(xq1.w) };
            short8 a9 = (short8){ (short)f2bf(xq2.x), (short)f2bf(xq2.y),
                                  (short)f2bf(xq2.z), (short)f2bf(xq2.w),
                                  (short)f2bf(xq3.x), (short)f2bf(xq3.y),
                                  (short)f2bf(xq3.z), (short)f2bf(xq3.w) };
            bf16x8 bv8 = __builtin_bit_cast(bf16x8, a8);
            bf16x8 bv9 = __builtin_bit_cast(bf16x8, a9);
            #pragma unroll
            for (int g = 0; g < 4; ++g) {
                acc[g] = __builtin_amdgcn_mfma_f32_16x16x32_bf16(wfrag[8][g], bv8, acc[g], 0, 0, 0);
                acc[g] = __builtin_amdgcn_mfma_f32_16x16x32_bf16(wfrag[9][g], bv9, acc[g], 0, 0, 0);
            }
        }

        // 2) wait for h_t, then ONE fused block: 8 parallel MALL loads + wait
        if (t > 0) {
            const unsigned target = 4u * (unsigned)t;
            if (lane == 0) {
                while (__hip_atomic_load(cnt, __ATOMIC_RELAXED,
                                         __HIP_MEMORY_SCOPE_AGENT) < target) {}
            }
            __builtin_amdgcn_sched_barrier(0);   // loads stay below the poll
            const unsigned short* hin = (t & 1) ? h1buf : h0buf;
            const void* haddr = hin + batch * 256 + lhi * 8;  // 16B aligned
            int4v h0, h1, h2, h3, h4, h5, h6, h7;
            asm volatile(
                "global_load_dwordx4 %0, %8, off sc0 sc1\n\t"
                "global_load_dwordx4 %1, %8, off offset:64 sc0 sc1\n\t"
                "global_load_dwordx4 %2, %8, off offset:128 sc0 sc1\n\t"
                "global_load_dwordx4 %3, %8, off offset:192 sc0 sc1\n\t"
                "global_load_dwordx4 %4, %8, off offset:256 sc0 sc1\n\t"
                "global_load_dwordx4 %5, %8, off offset:320 sc0 sc1\n\t"
                "global_load_dwordx4 %6, %8, off offset:384 sc0 sc1\n\t"
                "global_load_dwordx4 %7, %8, off offset:448 sc0 sc1\n\t"
                "s_waitcnt vmcnt(0)"
                : "=&v"(h0), "=&v"(h1), "=&v"(h2), "=&v"(h3),
                  "=&v"(h4), "=&v"(h5), "=&v"(h6), "=&v"(h7)
                : "v"(haddr)
                : "memory");
            int4v hvv[8] = { h0, h1, h2, h3, h4, h5, h6, h7 };
            #pragma unroll
            for (int ks = 0; ks < 8; ++ks) {
                bf16x8 bv = __builtin_bit_cast(bf16x8, hvv[ks]);
                #pragma unroll
                for (int g = 0; g < 4; ++g)
                    acc[g] = __builtin_amdgcn_mfma_f32_16x16x32_bf16(
                        wfrag[ks][g], bv, acc[g], 0, 0, 0);
            }
        }

        // 3) gates + c/h update; pack 4 consecutive-hidx h -> one u64 SWAP
        unsigned short* hout = ((t + 1) & 1) ? h1buf : h0buf;
        unsigned long long hpack = 0;
        #pragma unroll
        for (int r = 0; r < 4; ++r) {
            float cn = sigf(acc[1][r]) * creg[r] + sigf(acc[0][r]) * tanh_fast(acc[2][r]);
            float hn = sigf(acc[3][r]) * tanh_fast(cn);
            creg[r] = cn;
            hpack |= (unsigned long long)f2bf(hn) << (16 * r);
        }
        {
            unsigned long long* hp = reinterpret_cast<unsigned long long*>(
                hout + batch * 256 + h16 * 16 + lhi * 4);
            (void)__hip_atomic_exchange(hp, hpack, __ATOMIC_RELAXED,
                                        __HIP_MEMORY_SCOPE_AGENT);
        }

        // 4) prefetch x for t+1 (plain cached; drained by the barrier)
        if (t + 1 < Tt) {
            const float* xp = xrow + (size_t)(t + 1) * Dd;
            xq0 = *reinterpret_cast<const float4*>(xp);
            xq1 = *reinterpret_cast<const float4*>(xp + 4);
            xq2 = *reinterpret_cast<const float4*>(xp + 32);
            xq3 = *reinterpret_cast<const float4*>(xp + 36);
        }

        // 5) publish: barrier (drains the swap via vmcnt(0)) + relaxed add
        __syncthreads();
        if (tid == 0) {
            __hip_atomic_fetch_add(cnt, 1u, __ATOMIC_RELAXED,
                                   __HIP_MEMORY_SCOPE_AGENT);
        }
    }

    // --- output head: p==0 WGs handle their 16 batches (one-time acquire) --
    if (p == 0) {
        if (lane == 0) {
            while (__hip_atomic_load(cnt, __ATOMIC_RELAXED,
                                     __HIP_MEMORY_SCOPE_AGENT) < 4u * Tt) {}
        }
        __builtin_amdgcn_fence(__ATOMIC_ACQUIRE, "agent");
        const unsigned short* hT = h0buf;   // Tt even -> final h in buf 0
        #pragma unroll 1
        for (int rr = 0; rr < 4; ++rr) {
            int row = bg * 16 + w * 4 + rr;
            ushort4 hu = *reinterpret_cast<const ushort4*>(hT + row * 256 + lane * 4);
            float f0 = bf2f(hu.x), f1 = bf2f(hu.y), f2 = bf2f(hu.z), f3 = bf2f(hu.w);
            #pragma unroll 1
            for (int cls = 0; cls < CC; ++cls) {
                float4 wv = *reinterpret_cast<const float4*>(W_out + cls * 256 + lane * 4);
                float pr = f0 * wv.x + f1 * wv.y + f2 * wv.z + f3 * wv.w;
                #pragma unroll
                for (int off = 32; off > 0; off >>= 1) pr += __shfl_down(pr, off);
                if (lane == 0) out[row * CC + cls] = sigf(pr + b_out[cls]);
            }
        }
    }
}

extern "C" void kernel_launch(void* const* d_in, const int* in_sizes, int n_in,
                              void* d_out, int out_size, void* d_ws, size_t ws_size,
                              hipStream_t stream) {
    const float* x     = (const float*)d_in[0];
    const float* W_ih  = (const float*)d_in[1];
    const float* W_hh  = (const float*)d_in[2];
    const float* b_ih  = (const float*)d_in[3];
    const float* b_hh  = (const float*)d_in[4];
    const float* W_out = (const float*)d_in[5];
    const float* b_out = (const float*)d_in[6];
    float* out = (float*)d_out;

    // workspace layout (~924 KB)
    char* ws = (char*)d_ws;
    unsigned short* Wc    = (unsigned short*)(ws);            // 655360 B
    float*          biasp = (float*)(ws + 655360);            //   4096 B
    unsigned short* h0    = (unsigned short*)(ws + 659456);   // 131072 B
    unsigned short* h1    = (unsigned short*)(ws + 790528);   // 131072 B
    unsigned int*   arr   = (unsigned int*)(ws + 921600);     //   2048 B

    hipLaunchKernelGGL(prep_weights, dim3(1280), dim3(256), 0, stream, W_ih, W_hh, Wc);
    hipLaunchKernelGGL(prep_bias,    dim3(4),    dim3(256), 0, stream, b_ih, b_hh, biasp);
    hipMemsetAsync(arr, 0, 2048, stream);

    hipLaunchKernelGGL(lstm_persist, dim3(64), dim3(256), 0, stream,
                       x, Wc, biasp, h0, h1, arr, W_out, b_out, out);
}